// Round 3
// baseline (412.060 us; speedup 1.0000x reference)
//
#include <hip/hip_runtime.h>

// Problem constants (fixed by reference: seq (16,4096,1024) fp32, prune 0.5)
#define BATCH 16
#define NTOK  4096
#define DIM   1024
#define KSEL  2048                       // kept tokens
#define NPRUNE 2048                      // pruned tokens

#define GROWS 32                         // rows per gather block (128 KB)
#define GBLK (NTOK / GROWS)              // 128 gather blocks per batch
#define PARTS 8                          // threads cooperating per row rank
#define SPAN (NTOK / PARTS)              // 512 compares per cooperating thread

typedef __attribute__((ext_vector_type(4))) float f32x4;

// ---------------------------------------------------------------------------
// Fused rank + streaming gather. One block = 32 consecutive seq rows.
// Phase A (rank, ~2 us VALU/LDS, hidden under other blocks' streaming):
//   keyify the batch's full w row into LDS as u64 keys
//   key(i) = (~sortable(w_i) << 32) | i  — ascending u64 order ==
//   jax.lax.top_k order (value desc, index asc); exact all-pairs rank of
//   this block's 32 rows, 8 threads x 512 LDS compares per row.
//   Index rotation (k + 2p) keeps the 8 per-wave broadcast groups on
//   distinct LDS banks (stride-512 u64 would be 8-way same-bank).
// Phase B (stream, BW-bound): read 32 rows perfectly sequentially
//   (nontemporal), scatter-write kept rows to out[rank] (uniform per row),
//   accumulate pruned rows in-register, one partial row per block.
// grid (GBLK, BATCH), block = 256 (DIM/4 lanes = 1 f32x4 per lane per row).
// LDS 33 KB -> 4 blocks/CU resident.
// ---------------------------------------------------------------------------
__global__ __launch_bounds__(256) void gather_rank_kernel(
    const float* __restrict__ seq, const float* __restrict__ w,
    float* __restrict__ out, float* __restrict__ part) {
  __shared__ unsigned long long s_key[NTOK];      // 32 KB
  __shared__ int s_rank[GROWS];

  const int b = blockIdx.y, g = blockIdx.x;
  const int t = threadIdx.x;
  const float* wb = w + (size_t)b * NTOK;

  // --- keyify w into LDS (coalesced f32x4 loads; L2/L3-hot after block 0)
  const f32x4* w4 = (const f32x4*)wb;
#pragma unroll
  for (int k = 0; k < NTOK / (256 * 4); ++k) {    // 4 iters
    const int i4 = k * 256 + t;
    const f32x4 x = w4[i4];
#pragma unroll
    for (int c = 0; c < 4; ++c) {
      const int j = i4 * 4 + c;
      const unsigned int u = __float_as_uint(x[c]);
      const unsigned int s = (u & 0x80000000u) ? ~u : (u | 0x80000000u);
      s_key[j] = ((unsigned long long)(~s) << 32) | (unsigned int)j;
    }
  }
  __syncthreads();

  // --- exact rank of this block's 32 rows: row = t>>3, 8 parts per row
  const int row = t >> 3;                         // 0..31
  const int p = t & 7;                            // 0..7
  const int tok = g * GROWS + row;
  const unsigned long long ki = s_key[tok];
  unsigned int cnt = 0;
  const int base = p * SPAN;
#pragma unroll 8
  for (int k = 0; k < SPAN; ++k) {
    const int j = base + ((k + 2 * p) & (SPAN - 1));  // bank-staggered
    cnt += (s_key[j] < ki);
  }
  // sum the 8 partial counts (parts are 8 consecutive lanes of a wave)
  cnt += __shfl_down(cnt, 4, 8);
  cnt += __shfl_down(cnt, 2, 8);
  cnt += __shfl_down(cnt, 1, 8);
  if (p == 0) s_rank[row] = (int)cnt;
  __syncthreads();

  // --- stream 32 rows; scatter kept, accumulate pruned
  const int lane = t;                             // 256 = DIM/4
  const f32x4* src = (const f32x4*)(seq + (size_t)b * NTOK * DIM) +
                     (size_t)g * GROWS * (DIM / 4);
  f32x4* outb = (f32x4*)(out + (size_t)b * (KSEL + 1) * DIM);
  f32x4 acc = {0.f, 0.f, 0.f, 0.f};
#pragma unroll 8
  for (int i = 0; i < GROWS; ++i) {
    const f32x4 x = __builtin_nontemporal_load(src + (size_t)i * (DIM / 4) + lane);
    const int r = s_rank[i];                      // uniform broadcast
    if (r < KSEL) {
      __builtin_nontemporal_store(x, outb + (size_t)r * (DIM / 4) + lane);
    } else {
      acc += x;
    }
  }
  f32x4* pdst = (f32x4*)(part + ((size_t)b * GBLK + g) * DIM);
  pdst[lane] = acc;                               // cached: reduce reads it
}

// ---------------------------------------------------------------------------
// Reduce GBLK partials per batch, scale, write out row KSEL.
// grid (4, BATCH): each block owns a quarter of DIM; 4 thread-groups sum
// 32 chunks each, combine through LDS.
// ---------------------------------------------------------------------------
__global__ __launch_bounds__(256) void reduce_kernel(
    const float* __restrict__ part, float* __restrict__ out, float scale) {
  __shared__ f32x4 s_acc[4][64];
  const int b = blockIdx.y, qq = blockIdx.x;
  const int t = threadIdx.x, g = t >> 6, col = t & 63;
  const int c4 = qq * 64 + col;                   // float4 column in [0,256)
  const f32x4* p = (const f32x4*)(part + (size_t)b * GBLK * DIM);
  f32x4 acc = {0.f, 0.f, 0.f, 0.f};
#pragma unroll
  for (int i = 0; i < GBLK / 4; ++i) {
    const int ch = g + 4 * i;
    acc += p[(size_t)ch * (DIM / 4) + c4];
  }
  s_acc[g][col] = acc;
  __syncthreads();
  if (g == 0) {
    f32x4 r = (s_acc[0][col] + s_acc[1][col]) + (s_acc[2][col] + s_acc[3][col]);
    r *= scale;
    f32x4* dst = (f32x4*)(out + (size_t)b * (KSEL + 1) * DIM +
                          (size_t)KSEL * DIM);
    dst[c4] = r;
  }
}

extern "C" void kernel_launch(void* const* d_in, const int* in_sizes, int n_in,
                              void* d_out, int out_size, void* d_ws, size_t ws_size,
                              hipStream_t stream) {
  (void)in_sizes; (void)n_in; (void)out_size; (void)ws_size;
  const float* seq = (const float*)d_in[0];
  const float* w   = (const float*)d_in[1];
  float* out = (float*)d_out;

  float* part = (float*)d_ws;                    // BATCH*GBLK*DIM floats (8 MB)

  gather_rank_kernel<<<dim3(GBLK, BATCH), 256, 0, stream>>>(seq, w, out, part);
  const float scale = (float)(0.05 / (2048.0 + 1e-10));
  reduce_kernel<<<dim3(4, BATCH), 256, 0, stream>>>(part, out, scale);
}